// Round 5
// baseline (620.681 us; speedup 1.0000x reference)
//
#include <hip/hip_runtime.h>
#include <stdint.h>

// SuperpointGenerator v4b: dense voxel counts, phase-split scatter (L2-resident),
// nontemporal streaming, fully-parallel top-512 selection.
// B=32, N=2^18. Pipeline:
//   K1 scatter_counts x2: 16 batches/phase -> 2 dense arrays per XCD L2 (2.5 MB)
//   K2a hist_pass:     per-block 256-bin histograms of counts
//   K2b select_params: T, A=#{c>T}, m, per-block winner/tier bases
//   K2c collect:       winners (c>T) + id-ordered tier (c==T)
//   K2d rank512:       rank by (count desc, id asc) -> packed lookup table
//   K3 write_labels:   binary-search packed table in LDS

#define BATCHES   32
#define NPTS      (1 << 18)
#define MAX_SP    512
#define DRANGE    1245184            // bytes per batch; covers |id| <= 622592
#define OFFSET    (DRANGE / 2)
#define DWORDS    (DRANGE / 4)       // 311296
#define NB        76                 // blocks per batch in scan kernels
#define BLK_DW    4096               // dwords per block (76*4096 = 311296)
#define TIERCAP   18432

typedef uint32_t u32x4 __attribute__((ext_vector_type(4)));   // nontemporal-compatible

__device__ __forceinline__ int point_idx_nt(const float* __restrict__ c3) {
    float x = __builtin_nontemporal_load(c3 + 0);
    float y = __builtin_nontemporal_load(c3 + 1);
    float z = __builtin_nontemporal_load(c3 + 2);
    int vx = (int)(x / 0.2f);        // IEEE f32 divide + trunc-to-zero == ref
    int vy = (int)(y / 0.2f);
    int vz = (int)(z / 0.2f);
    int id = vx * 10000 + vy * 100 + vz;
    int idx = id + OFFSET;
    idx = idx < 0 ? 0 : (idx >= DRANGE ? DRANGE - 1 : idx);  // memory safety only
    return idx;
}

// ---- K1: byte-packed atomicAdd per point; 16 batches per phase ----
// batch = base + (blockIdx & 15): with round-robin block->XCD, batches sharing
// XCD k are {base+k, base+k+8} -> 2 x 1.24 MB dense arrays resident per L2.
__global__ void __launch_bounds__(256) scatter_counts(
    const float* __restrict__ coords, uint32_t* __restrict__ dense,
    int* __restrict__ vidx, int batch_base)
{
    int b  = batch_base + (blockIdx.x & 15);
    int pt = (blockIdx.x >> 4) * 256 + threadIdx.x;
    int idx = point_idx_nt(coords + ((size_t)b * NPTS + pt) * 3);
    __builtin_nontemporal_store(idx, &vidx[(size_t)b * NPTS + pt]);
    uint32_t* dw = dense + (size_t)b * DWORDS;
    atomicAdd(&dw[idx >> 2], 1u << ((idx & 3) * 8));
}

// ---- K2a: per-block 256-bin histogram of voxel counts ----
__global__ void __launch_bounds__(256) hist_pass(
    const uint32_t* __restrict__ dense, int* __restrict__ blockhist)
{
    int b = blockIdx.x & 31, blk = blockIdx.x >> 5, tid = threadIdx.x;
    __shared__ int h[256];
    h[tid] = 0;
    __syncthreads();
    const u32x4* dwb = (const u32x4*)(dense + (size_t)b * DWORDS + (size_t)blk * BLK_DW);
    #pragma unroll
    for (int k = 0; k < 4; ++k) {                // coalesced: 4096 dwords = 1024 x 16B
        u32x4 v = __builtin_nontemporal_load(&dwb[k * 256 + tid]);
        #pragma unroll
        for (int d = 0; d < 4; ++d) {
            uint32_t w = v[d];
            if (!w) continue;
            #pragma unroll
            for (int j = 0; j < 4; ++j) {
                uint32_t c = (w >> (j * 8)) & 255u;
                if (c) atomicAdd(&h[c], 1);
            }
        }
    }
    __syncthreads();
    blockhist[(b * NB + blk) * 256 + tid] = h[tid];
}

// ---- K2b: derive T/A/m/nu and per-block winner/tier exclusive bases ----
__global__ void __launch_bounds__(256) select_params(
    const int* __restrict__ blockhist, int* __restrict__ params,
    int* __restrict__ wbase, int* __restrict__ tbase)
{
    int b = blockIdx.x, tid = threadIdx.x;
    __shared__ int tot[256];
    __shared__ int wc_[NB], tc_[NB];
    __shared__ int sh_T;
    int s = 0;
    for (int k = 0; k < NB; ++k) s += blockhist[(b * NB + k) * 256 + tid];
    tot[tid] = s;
    __syncthreads();
    if (tid == 0) {
        int nu = 0;
        for (int c = 1; c < 256; ++c) nu += tot[c];
        int acc = 0, c = 255;
        while (c > 1 && acc + tot[c] < MAX_SP) { acc += tot[c]; --c; }
        int T = c, A = acc;
        int m = MAX_SP - A; if (m > tot[T]) m = tot[T];   // nu<=512: take whole tier
        params[b * 8 + 0] = T;  params[b * 8 + 1] = A;
        params[b * 8 + 2] = m;  params[b * 8 + 3] = nu;
        params[b * 8 + 4] = A + m;                        // nw = min(512, nu)
        sh_T = T;
    }
    __syncthreads();
    int T = sh_T;
    if (tid < NB) {
        int ws = 0;
        const int* bh = blockhist + (b * NB + tid) * 256;
        for (int c = T + 1; c < 256; ++c) ws += bh[c];
        wc_[tid] = ws;
        tc_[tid] = bh[T];
    }
    __syncthreads();
    if (tid == 0) {
        int aw = 0, at = 0;
        for (int k = 0; k < NB; ++k) {
            wbase[b * NB + k] = aw; tbase[b * NB + k] = at;
            aw += wc_[k]; at += tc_[k];
        }
    }
}

// ---- K2c: gather winners (any order) + tier members (exact id order) ----
__global__ void __launch_bounds__(256) collect(
    const uint32_t* __restrict__ dense, const int* __restrict__ params,
    const int* __restrict__ wbase, const int* __restrict__ tbase,
    uint32_t* __restrict__ wid, int* __restrict__ wcnt, uint32_t* __restrict__ tier)
{
    int b = blockIdx.x & 31, blk = blockIdx.x >> 5, tid = threadIdx.x;
    int T = params[b * 8 + 0], m = params[b * 8 + 2];
    int wb = wbase[b * NB + blk], tb = tbase[b * NB + blk];
    __shared__ int wpos;
    __shared__ int tl[256];
    if (tid == 0) wpos = 0;
    __syncthreads();

    // per-thread CONTIGUOUS 16 dwords: preserves id order within thread, tid order across
    const u32x4* dwb = (const u32x4*)(dense + (size_t)b * DWORDS + (size_t)blk * BLK_DW);
    u32x4 v[4];
    #pragma unroll
    for (int k = 0; k < 4; ++k) v[k] = __builtin_nontemporal_load(&dwb[tid * 4 + k]);

    int base_id = (blk * BLK_DW + tid * 16) * 4;     // dense byte index of first element
    int ntier = 0;
    #pragma unroll
    for (int k = 0; k < 4; ++k) {
        #pragma unroll
        for (int d = 0; d < 4; ++d) {
            uint32_t w = v[k][d];
            if (!w) continue;
            #pragma unroll
            for (int j = 0; j < 4; ++j) {
                int c = (int)((w >> (j * 8)) & 255u);
                if (c > T) {
                    int p = atomicAdd(&wpos, 1);
                    wid [b * MAX_SP + wb + p] = (uint32_t)(base_id + (k * 4 + d) * 4 + j);
                    wcnt[b * MAX_SP + wb + p] = c;
                } else if (c == T) ++ntier;
            }
        }
    }
    tl[tid] = ntier;
    __syncthreads();
    if (tb < m && ntier > 0) {                       // only blocks that can hold tier[0..m)
        int pre = 0;
        for (int j = 0; j < 256; ++j) { int t = tl[j]; if (j < tid) pre += t; }
        int pos = tb + pre, kk = 0;
        #pragma unroll
        for (int k = 0; k < 4; ++k) {
            #pragma unroll
            for (int d = 0; d < 4; ++d) {
                uint32_t w = v[k][d];
                if (!w) continue;
                #pragma unroll
                for (int j = 0; j < 4; ++j) {
                    int c = (int)((w >> (j * 8)) & 255u);
                    if (c == T) {
                        int q = pos + kk; ++kk;
                        if (q < TIERCAP) tier[b * TIERCAP + q] = (uint32_t)(base_id + (k * 4 + d) * 4 + j);
                    }
                }
            }
        }
    }
}

// ---- K2d: rank 512 winners; emit PACKED table (idx<<9 | label), sorted by idx ----
__global__ void __launch_bounds__(512) rank512(
    const int* __restrict__ params, const uint32_t* __restrict__ wid,
    const int* __restrict__ wcnt, const uint32_t* __restrict__ tier,
    uint32_t* __restrict__ lookup, int* __restrict__ counters)
{
    int b = blockIdx.x, tid = threadIdx.x;
    int T = params[b * 8 + 0], A = params[b * 8 + 1];
    int nu = params[b * 8 + 3], nw = params[b * 8 + 4];
    __shared__ uint32_t wu[MAX_SP];
    __shared__ int      wc[MAX_SP];
    if (tid < A)       { wu[tid] = wid[b * MAX_SP + tid]; wc[tid] = wcnt[b * MAX_SP + tid]; }
    else if (tid < nw) { wu[tid] = tier[b * TIERCAP + (tid - A)]; wc[tid] = T; }
    __syncthreads();
    if (tid < nw) {
        uint32_t u = wu[tid]; int c = wc[tid];
        int r = 0, ur = 0;
        for (int j = 0; j < nw; ++j) {
            uint32_t uj = wu[j]; int cj = wc[j];
            r  += ((cj > c) || (cj == c && uj < u)) ? 1 : 0;
            ur += (uj < u) ? 1 : 0;
        }
        int label = (nu <= MAX_SP) ? ur : r;         // inverse branch: id-rank
        lookup[b * MAX_SP + ur] = (u << 9) | (uint32_t)label;   // idx<21b, label<9b
    }
    if (tid == 0) counters[b] = nw;
}

// ---- K3: label each point via binary search of packed LDS table ----
__global__ void __launch_bounds__(256) write_labels(
    const int* __restrict__ vidx, const int* __restrict__ counters,
    const uint32_t* __restrict__ lookup, int* __restrict__ out)
{
    __shared__ uint32_t lu[MAX_SP];
    __shared__ int      sh_nw;
    int b  = blockIdx.x & 31;
    int pt = (blockIdx.x >> 5) * 256 + threadIdx.x;
    if (threadIdx.x == 0) sh_nw = counters[b];
    lu[threadIdx.x]       = lookup[b * MAX_SP + threadIdx.x];
    lu[threadIdx.x + 256] = lookup[b * MAX_SP + threadIdx.x + 256];
    __syncthreads();
    int nw = sh_nw;
    uint32_t u = (uint32_t)__builtin_nontemporal_load(&vidx[(size_t)b * NPTS + pt]);
    int lo = 0, hi = nw;
    while (lo < hi) { int mid = (lo + hi) >> 1; if ((lu[mid] >> 9) < u) lo = mid + 1; else hi = mid; }
    int label = 0;
    if (lo < nw && (lu[lo] >> 9) == u) label = (int)(lu[lo] & 511u);
    __builtin_nontemporal_store(label, &out[(size_t)b * NPTS + pt]);
}

extern "C" void kernel_launch(void* const* d_in, const int* in_sizes, int n_in,
                              void* d_out, int out_size, void* d_ws, size_t ws_size,
                              hipStream_t stream) {
    const float* coords = (const float*)d_in[0];
    int* out = (int*)d_out;

    uint8_t* p = (uint8_t*)d_ws;
    uint32_t* dense     = (uint32_t*)p; p += (size_t)BATCHES * DRANGE;            // 39.9 MB
    int*      vidx      = (int*)p;      p += (size_t)BATCHES * NPTS * 4;          // 33.6 MB
    int*      blockhist = (int*)p;      p += (size_t)BATCHES * NB * 256 * 4;      // 2.5 MB
    uint32_t* tier      = (uint32_t*)p; p += (size_t)BATCHES * TIERCAP * 4;       // 2.4 MB
    int*      wbase     = (int*)p;      p += (size_t)BATCHES * NB * 4;
    int*      tbase     = (int*)p;      p += (size_t)BATCHES * NB * 4;
    int*      params    = (int*)p;      p += (size_t)BATCHES * 8 * 4;
    uint32_t* wid       = (uint32_t*)p; p += (size_t)BATCHES * MAX_SP * 4;
    int*      wcnt      = (int*)p;      p += (size_t)BATCHES * MAX_SP * 4;
    int*      counters  = (int*)p;      p += (size_t)BATCHES * 4;
    uint32_t* lookup    = (uint32_t*)p; p += (size_t)BATCHES * MAX_SP * 4;

    (void)hipMemsetAsync(dense, 0, (size_t)BATCHES * DRANGE, stream);

    int half = (BATCHES / 2) * NPTS;
    scatter_counts<<<half / 256, 256, 0, stream>>>(coords, dense, vidx, 0);
    scatter_counts<<<half / 256, 256, 0, stream>>>(coords, dense, vidx, 16);
    hist_pass     <<<BATCHES * NB, 256, 0, stream>>>(dense, blockhist);
    select_params <<<BATCHES, 256, 0, stream>>>(blockhist, params, wbase, tbase);
    collect       <<<BATCHES * NB, 256, 0, stream>>>(dense, params, wbase, tbase, wid, wcnt, tier);
    rank512       <<<BATCHES, 512, 0, stream>>>(params, wid, wcnt, tier, lookup, counters);
    write_labels  <<<BATCHES * NPTS / 256, 256, 0, stream>>>(vidx, counters, lookup, out);
}

// Round 6
// 382.718 us; speedup vs baseline: 1.6218x; 1.6218x over previous
//
#include <hip/hip_runtime.h>
#include <stdint.h>

// SuperpointGenerator v5: global-atomic-free counting via LDS multisplit.
// Finding (R5): global atomicAdd on gfx950 costs ~32 B HBM write each
// (memory-side execution for cross-XCD atomicity) -> 8.4M atomics = hard
// ~372 us floor. Fix: bucket points by vidx>>14 (76 buckets == dense range),
// then count each 16K-voxel bucket in LDS with LDS atomics only.
// Pipeline:
//   K1  compute_vidx_count: vidx per point + per-(block,bucket) counts
//   K1b scan_buckets:       bases per (block,bucket), bucket totals
//   K1c scatter_lists:      vidx -> bucket-segmented lists (no global atomics)
//   K2  count_bucket:       LDS byte counts -> dense slice + 256-bin histogram
//   K2b select_params:      T, A=#{c>T}, m, per-bucket winner/tier bases
//   K2c collect:            winners (c>T) + id-ordered tier (c==T)
//   K2d rank512:            rank by (count desc, id asc) -> packed lookup
//   K3  write_labels:       binary-search packed table in LDS

#define BATCHES   32
#define NPTS      (1 << 18)
#define MAX_SP    512
#define NBUK      76
#define BUK_VOX   16384              // voxels per bucket (16 KB LDS byte counters)
#define DRANGE    (NBUK * BUK_VOX)   // 1245184, same coverage as v2..v4
#define OFFSET    (DRANGE / 2)       // 622592
#define DWORDS    (DRANGE / 4)       // 311296
#define BUK_DW    (BUK_VOX / 4)      // 4096 dwords per bucket
#define TIERCAP   18432              // >= 512 + 16384 (one full bucket of tier)

typedef uint32_t u32x4 __attribute__((ext_vector_type(4)));

__device__ __forceinline__ int point_idx_nt(const float* __restrict__ c3) {
    float x = __builtin_nontemporal_load(c3 + 0);
    float y = __builtin_nontemporal_load(c3 + 1);
    float z = __builtin_nontemporal_load(c3 + 2);
    int vx = (int)(x / 0.2f);        // IEEE f32 divide + trunc-to-zero == ref
    int vy = (int)(y / 0.2f);
    int vz = (int)(z / 0.2f);
    int id = vx * 10000 + vy * 100 + vz;
    int idx = id + OFFSET;
    idx = idx < 0 ? 0 : (idx >= DRANGE ? DRANGE - 1 : idx);  // memory safety only
    return idx;
}

// ---- K1: vidx per point + per-(block,bucket) counts (LDS atomics only) ----
__global__ void __launch_bounds__(1024) compute_vidx_count(
    const float* __restrict__ coords, int* __restrict__ vidx,
    int* __restrict__ blkcnt)
{
    int b = blockIdx.x >> 8, blk = blockIdx.x & 255, tid = threadIdx.x;
    __shared__ int cnt[NBUK];
    if (tid < NBUK) cnt[tid] = 0;
    __syncthreads();
    size_t pt = (size_t)b * NPTS + blk * 1024 + tid;
    int idx = point_idx_nt(coords + pt * 3);
    __builtin_nontemporal_store(idx, &vidx[pt]);
    atomicAdd(&cnt[idx >> 14], 1);
    __syncthreads();
    if (tid < NBUK)
        blkcnt[((size_t)b * 256 + blk) * NBUK + tid] = cnt[tid];   // contiguous per block
}

// ---- K1b: per-batch scan -> blkbase[(b,blk,k)] and buktot[b][k] ----
__global__ void __launch_bounds__(128) scan_buckets(
    const int* __restrict__ blkcnt, int* __restrict__ blkbase,
    int* __restrict__ buktot)
{
    int b = blockIdx.x, tid = threadIdx.x;
    __shared__ int c[256 * NBUK];    // 76 KB: whole batch's counts
    __shared__ int start[NBUK];
    for (int i = tid; i < 256 * NBUK; i += 128)
        c[i] = blkcnt[(size_t)b * 256 * NBUK + i];
    __syncthreads();
    if (tid < NBUK) {
        int s = 0;
        for (int blk = 0; blk < 256; ++blk) s += c[blk * NBUK + tid];
        buktot[b * NBUK + tid] = s;
        start[tid] = s;
    }
    __syncthreads();
    if (tid == 0) {
        int run = 0;
        for (int k = 0; k < NBUK; ++k) { int t = start[k]; start[k] = run; run += t; }
    }
    __syncthreads();
    if (tid < NBUK) {
        int run = start[tid];
        for (int blk = 0; blk < 256; ++blk) {
            size_t o = ((size_t)b * 256 + blk) * NBUK + tid;
            blkbase[o] = run;
            run += c[blk * NBUK + tid];
        }
    }
}

// ---- K1c: scatter vidx into bucket-segmented lists (no global atomics) ----
__global__ void __launch_bounds__(1024) scatter_lists(
    const int* __restrict__ vidx, const int* __restrict__ blkbase,
    int* __restrict__ lists)
{
    int b = blockIdx.x >> 8, blk = blockIdx.x & 255, tid = threadIdx.x;
    __shared__ int pos[NBUK];
    if (tid < NBUK) pos[tid] = blkbase[((size_t)b * 256 + blk) * NBUK + tid];
    __syncthreads();
    size_t pt = (size_t)b * NPTS + blk * 1024 + tid;
    int idx = __builtin_nontemporal_load(&vidx[pt]);
    int p = atomicAdd(&pos[idx >> 14], 1);
    __builtin_nontemporal_store(idx, &lists[(size_t)b * NPTS + p]);
}

// ---- K2: per-(batch,bucket) LDS byte counting -> dense slice + histogram ----
__global__ void __launch_bounds__(1024) count_bucket(
    const int* __restrict__ lists, const int* __restrict__ blkbase,
    const int* __restrict__ buktot, uint32_t* __restrict__ dense,
    int* __restrict__ blockhist)
{
    int k = blockIdx.x, b = blockIdx.y, tid = threadIdx.x;
    __shared__ uint32_t cnt[BUK_DW];     // 16 KB byte counters
    __shared__ uint32_t h16[16 * 256];   // 16 KB per-wave count histogram
    for (int i = tid; i < BUK_DW; i += 1024) cnt[i] = 0;
    for (int i = tid; i < 16 * 256; i += 1024) h16[i] = 0;
    __syncthreads();
    int start = blkbase[(size_t)b * 256 * NBUK + k];   // blk 0 base == segment start
    int n = buktot[b * NBUK + k];
    const int* seg = lists + (size_t)b * NPTS + start;
    for (int i = tid; i < n; i += 1024) {
        int idx = seg[i] & (BUK_VOX - 1);
        atomicAdd(&cnt[idx >> 2], 1u << ((idx & 3) * 8));
    }
    __syncthreads();
    int rep = tid >> 6;                                 // wave id 0..15
    uint32_t* dw = dense + (size_t)b * DWORDS + (size_t)k * BUK_DW;
    for (int i = tid; i < BUK_DW; i += 1024) {
        uint32_t w = cnt[i];
        __builtin_nontemporal_store(w, &dw[i]);
        if (w) {
            #pragma unroll
            for (int j = 0; j < 4; ++j) {
                uint32_t cc = (w >> (j * 8)) & 255u;
                if (cc) atomicAdd(&h16[rep * 256 + cc], 1u);
            }
        }
    }
    __syncthreads();
    if (tid < 256) {
        uint32_t s = 0;
        #pragma unroll
        for (int r = 0; r < 16; ++r) s += h16[r * 256 + tid];
        blockhist[((size_t)b * NBUK + k) * 256 + tid] = (int)s;
    }
}

// ---- K2b: derive T/A/m/nu and per-bucket winner/tier exclusive bases ----
__global__ void __launch_bounds__(256) select_params(
    const int* __restrict__ blockhist, int* __restrict__ params,
    int* __restrict__ wbase, int* __restrict__ tbase)
{
    int b = blockIdx.x, tid = threadIdx.x;
    __shared__ int tot[256];
    __shared__ int wc_[NBUK], tc_[NBUK];
    __shared__ int sh_T;
    int s = 0;
    for (int k = 0; k < NBUK; ++k) s += blockhist[((size_t)b * NBUK + k) * 256 + tid];
    tot[tid] = s;
    __syncthreads();
    if (tid == 0) {
        int nu = 0;
        for (int c = 1; c < 256; ++c) nu += tot[c];
        int acc = 0, c = 255;
        while (c > 1 && acc + tot[c] < MAX_SP) { acc += tot[c]; --c; }
        int T = c, A = acc;
        int m = MAX_SP - A; if (m > tot[T]) m = tot[T];   // nu<=512: take whole tier
        params[b * 8 + 0] = T;  params[b * 8 + 1] = A;
        params[b * 8 + 2] = m;  params[b * 8 + 3] = nu;
        params[b * 8 + 4] = A + m;                        // nw = min(512, nu)
        sh_T = T;
    }
    __syncthreads();
    int T = sh_T;
    if (tid < NBUK) {
        int ws = 0;
        const int* bh = blockhist + ((size_t)b * NBUK + tid) * 256;
        for (int c = T + 1; c < 256; ++c) ws += bh[c];
        wc_[tid] = ws;
        tc_[tid] = bh[T];
    }
    __syncthreads();
    if (tid == 0) {
        int aw = 0, at = 0;
        for (int k = 0; k < NBUK; ++k) {
            wbase[b * NBUK + k] = aw; tbase[b * NBUK + k] = at;
            aw += wc_[k]; at += tc_[k];
        }
    }
}

// ---- K2c: gather winners (any order) + tier members (exact id order) ----
__global__ void __launch_bounds__(256) collect(
    const uint32_t* __restrict__ dense, const int* __restrict__ params,
    const int* __restrict__ wbase, const int* __restrict__ tbase,
    uint32_t* __restrict__ wid, int* __restrict__ wcnt, uint32_t* __restrict__ tier)
{
    int k = blockIdx.x, b = blockIdx.y, tid = threadIdx.x;
    int T = params[b * 8 + 0], m = params[b * 8 + 2];
    int wb = wbase[b * NBUK + k], tb = tbase[b * NBUK + k];
    __shared__ int wpos;
    __shared__ int tl[256];
    if (tid == 0) wpos = 0;
    __syncthreads();

    // per-thread CONTIGUOUS 16 dwords: id order within thread, tid order across
    const u32x4* dwb = (const u32x4*)(dense + (size_t)b * DWORDS + (size_t)k * BUK_DW);
    u32x4 v[4];
    #pragma unroll
    for (int q = 0; q < 4; ++q) v[q] = __builtin_nontemporal_load(&dwb[tid * 4 + q]);

    int base_id = (k * BUK_DW + tid * 16) * 4;
    int ntier = 0;
    #pragma unroll
    for (int q = 0; q < 4; ++q) {
        #pragma unroll
        for (int d = 0; d < 4; ++d) {
            uint32_t w = v[q][d];
            if (!w) continue;
            #pragma unroll
            for (int j = 0; j < 4; ++j) {
                int c = (int)((w >> (j * 8)) & 255u);
                if (c > T) {
                    int p = atomicAdd(&wpos, 1);
                    wid [b * MAX_SP + wb + p] = (uint32_t)(base_id + (q * 4 + d) * 4 + j);
                    wcnt[b * MAX_SP + wb + p] = c;
                } else if (c == T) ++ntier;
            }
        }
    }
    tl[tid] = ntier;
    __syncthreads();
    if (tb < m && ntier > 0) {                       // only blocks that can hold tier[0..m)
        int pre = 0;
        for (int j = 0; j < 256; ++j) { int t = tl[j]; if (j < tid) pre += t; }
        int pos = tb + pre, kk = 0;
        #pragma unroll
        for (int q = 0; q < 4; ++q) {
            #pragma unroll
            for (int d = 0; d < 4; ++d) {
                uint32_t w = v[q][d];
                if (!w) continue;
                #pragma unroll
                for (int j = 0; j < 4; ++j) {
                    int c = (int)((w >> (j * 8)) & 255u);
                    if (c == T) {
                        int qq = pos + kk; ++kk;
                        if (qq < TIERCAP) tier[b * TIERCAP + qq] = (uint32_t)(base_id + (q * 4 + d) * 4 + j);
                    }
                }
            }
        }
    }
}

// ---- K2d: rank 512 winners; emit PACKED table (idx<<9 | label), sorted by idx ----
__global__ void __launch_bounds__(512) rank512(
    const int* __restrict__ params, const uint32_t* __restrict__ wid,
    const int* __restrict__ wcnt, const uint32_t* __restrict__ tier,
    uint32_t* __restrict__ lookup, int* __restrict__ counters)
{
    int b = blockIdx.x, tid = threadIdx.x;
    int T = params[b * 8 + 0], A = params[b * 8 + 1];
    int nu = params[b * 8 + 3], nw = params[b * 8 + 4];
    __shared__ uint32_t wu[MAX_SP];
    __shared__ int      wc[MAX_SP];
    if (tid < A)       { wu[tid] = wid[b * MAX_SP + tid]; wc[tid] = wcnt[b * MAX_SP + tid]; }
    else if (tid < nw) { wu[tid] = tier[b * TIERCAP + (tid - A)]; wc[tid] = T; }
    __syncthreads();
    if (tid < nw) {
        uint32_t u = wu[tid]; int c = wc[tid];
        int r = 0, ur = 0;
        for (int j = 0; j < nw; ++j) {
            uint32_t uj = wu[j]; int cj = wc[j];
            r  += ((cj > c) || (cj == c && uj < u)) ? 1 : 0;
            ur += (uj < u) ? 1 : 0;
        }
        int label = (nu <= MAX_SP) ? ur : r;         // inverse branch: id-rank
        lookup[b * MAX_SP + ur] = (u << 9) | (uint32_t)label;   // idx<21b, label<9b
    }
    if (tid == 0) counters[b] = nw;
}

// ---- K3: label each point via binary search of packed LDS table ----
__global__ void __launch_bounds__(256) write_labels(
    const int* __restrict__ vidx, const int* __restrict__ counters,
    const uint32_t* __restrict__ lookup, int* __restrict__ out)
{
    __shared__ uint32_t lu[MAX_SP];
    __shared__ int      sh_nw;
    int b  = blockIdx.x & 31;
    int pt = (blockIdx.x >> 5) * 256 + threadIdx.x;
    if (threadIdx.x == 0) sh_nw = counters[b];
    lu[threadIdx.x]       = lookup[b * MAX_SP + threadIdx.x];
    lu[threadIdx.x + 256] = lookup[b * MAX_SP + threadIdx.x + 256];
    __syncthreads();
    int nw = sh_nw;
    uint32_t u = (uint32_t)__builtin_nontemporal_load(&vidx[(size_t)b * NPTS + pt]);
    int lo = 0, hi = nw;
    while (lo < hi) { int mid = (lo + hi) >> 1; if ((lu[mid] >> 9) < u) lo = mid + 1; else hi = mid; }
    int label = 0;
    if (lo < nw && (lu[lo] >> 9) == u) label = (int)(lu[lo] & 511u);
    __builtin_nontemporal_store(label, &out[(size_t)b * NPTS + pt]);
}

extern "C" void kernel_launch(void* const* d_in, const int* in_sizes, int n_in,
                              void* d_out, int out_size, void* d_ws, size_t ws_size,
                              hipStream_t stream) {
    const float* coords = (const float*)d_in[0];
    int* out = (int*)d_out;

    uint8_t* p = (uint8_t*)d_ws;
    uint32_t* dense     = (uint32_t*)p; p += (size_t)BATCHES * DRANGE;            // 39.9 MB
    int*      vidx      = (int*)p;      p += (size_t)BATCHES * NPTS * 4;          // 33.6 MB
    int*      lists     = (int*)p;      p += (size_t)BATCHES * NPTS * 4;          // 33.6 MB
    int*      blkcnt    = (int*)p;      p += (size_t)BATCHES * 256 * NBUK * 4;    // 2.5 MB
    int*      blkbase   = (int*)p;      p += (size_t)BATCHES * 256 * NBUK * 4;    // 2.5 MB
    uint32_t* tier      = (uint32_t*)p; p += (size_t)BATCHES * TIERCAP * 4;       // 2.4 MB
    int*      buktot    = (int*)p;      p += (size_t)BATCHES * NBUK * 4;
    int*      wbase     = (int*)p;      p += (size_t)BATCHES * NBUK * 4;
    int*      tbase     = (int*)p;      p += (size_t)BATCHES * NBUK * 4;
    int*      params    = (int*)p;      p += (size_t)BATCHES * 8 * 4;
    uint32_t* wid       = (uint32_t*)p; p += (size_t)BATCHES * MAX_SP * 4;
    int*      wcnt      = (int*)p;      p += (size_t)BATCHES * MAX_SP * 4;
    int*      counters  = (int*)p;      p += (size_t)BATCHES * 4;
    uint32_t* lookup    = (uint32_t*)p; p += (size_t)BATCHES * MAX_SP * 4;
    int*      blockhist = blkcnt;       // alias: blkcnt dead after scan_buckets

    compute_vidx_count<<<BATCHES * 256, 1024, 0, stream>>>(coords, vidx, blkcnt);
    scan_buckets      <<<BATCHES, 128, 0, stream>>>(blkcnt, blkbase, buktot);
    scatter_lists     <<<BATCHES * 256, 1024, 0, stream>>>(vidx, blkbase, lists);
    count_bucket      <<<dim3(NBUK, BATCHES), 1024, 0, stream>>>(lists, blkbase, buktot, dense, blockhist);
    select_params     <<<BATCHES, 256, 0, stream>>>(blockhist, params, wbase, tbase);
    collect           <<<dim3(NBUK, BATCHES), 256, 0, stream>>>(dense, params, wbase, tbase, wid, wcnt, tier);
    rank512           <<<BATCHES, 512, 0, stream>>>(params, wid, wcnt, tier, lookup, counters);
    write_labels      <<<BATCHES * NPTS / 256, 256, 0, stream>>>(vidx, counters, lookup, out);
}